// Round 1
// baseline (448.288 us; speedup 1.0000x reference)
//
#include <hip/hip_runtime.h>
#include <hip/hip_bf16.h>

// Sizes (fixed by the reference)
#define RAG   2048          // BS*NA
#define NEN   16            // enemies
#define NALY  15            // allies
#define OWND  30
#define ALD   10
#define H     64
#define HD    4
#define KTRUE 650           // 65*10 (h1 augmented with 1.0) x feat dim
#define KDIM  656           // padded to multiple of 16
#define N256  256           // HD*H
#define AROWS 30720         // RAG*NALY
#define EROWS 32768         // RAG*NEN
#define QOFF  45056         // 128*16*22

// ---------------------------------------------------------------- K1: ha1_aug
__global__ void k_prep_ally(const float* __restrict__ af, const float* __restrict__ w1,
                            const float* __restrict__ b1, float* __restrict__ ha1) {
    int t = blockIdx.x * blockDim.x + threadIdx.x;
    int row = t >> 6, h = t & 63;
    if (row >= AROWS) return;
    const float* a = af + row * ALD;
    float s = b1[h];
#pragma unroll
    for (int i = 0; i < ALD; ++i) s = fmaf(a[i], w1[i * H + h], s);
    ha1[row * 65 + h] = fmaxf(s, 0.f);
    if (h == 0) ha1[row * 65 + 64] = 1.0f;
}

// ------------------------------------------------- K2: enemy Usum (sum over NE)
__global__ void k_enemy_usum(const float* __restrict__ ef, const float* __restrict__ w1,
                             const float* __restrict__ b1, float* __restrict__ usum) {
    __shared__ float s_ef[NEN * ALD];   // 160
    __shared__ float s_h[NEN * H];      // 1024
    int ag = blockIdx.x, tid = threadIdx.x;
    const float* e = ef + ag * NEN * ALD;
    if (tid < NEN * ALD) s_ef[tid] = e[tid];
    __syncthreads();
    for (int idx = tid; idx < NEN * H; idx += 256) {
        int en = idx >> 6, h = idx & 63;
        float s = b1[h];
#pragma unroll
        for (int i = 0; i < ALD; ++i) s = fmaf(s_ef[en * ALD + i], w1[i * H + h], s);
        s_h[idx] = fmaxf(s, 0.f);
    }
    __syncthreads();
    for (int k = tid; k < KDIM; k += 256) {
        float s = 0.f;
        if (k < KTRUE) {
            int h = k / 10, i = k - h * 10;
            if (h < 64) {
#pragma unroll
                for (int en = 0; en < NEN; ++en) s = fmaf(s_h[en * H + h], s_ef[en * ALD + i], s);
            } else {
#pragma unroll
                for (int en = 0; en < NEN; ++en) s += s_ef[en * ALD + i];
            }
        }
        usum[ag * KDIM + k] = s;
    }
}

// -------------------------------------------------- K3: ally Usum (sum over NAL)
__global__ void k_ally_usum(const float* __restrict__ af, const float* __restrict__ ha1,
                            float* __restrict__ usum) {
    __shared__ float s_af[NALY * ALD];  // 150
    __shared__ float s_h[NALY * 65];    // 975
    int ag = blockIdx.x, tid = threadIdx.x;
    const float* a = af + ag * NALY * ALD;
    const float* hh = ha1 + ag * NALY * 65;
    if (tid < NALY * ALD) s_af[tid] = a[tid];
    for (int idx = tid; idx < NALY * 65; idx += 256) s_h[idx] = hh[idx];
    __syncthreads();
    for (int k = tid; k < KDIM; k += 256) {
        float s = 0.f;
        if (k < KTRUE) {
            int h = k / 10, i = k - h * 10;   // h in [0,65): h==64 row is the aug (1.0)
#pragma unroll
            for (int l = 0; l < NALY; ++l) s = fmaf(s_h[l * 65 + h], s_af[l * ALD + i], s);
        }
        usum[ag * KDIM + k] = s;
    }
}

// --------------------------------- K4: reorder hypernet weights into [K=656,256]
__global__ void k_reorder_B(const float* __restrict__ he_w2, const float* __restrict__ he_b2,
                            const float* __restrict__ ha_w2, const float* __restrict__ ha_b2,
                            float* __restrict__ Be, float* __restrict__ Ba) {
    int k = blockIdx.x, o = threadIdx.x;
    float ve = 0.f, va = 0.f;
    if (k < KTRUE) {
        int h = k / 10, i = k - h * 10;
        if (h < 64) { ve = he_w2[h * 2820 + i * 256 + o]; va = ha_w2[h * 2560 + i * 256 + o]; }
        else        { ve = he_b2[i * 256 + o];            va = ha_b2[i * 256 + o]; }
    }
    Be[k * 256 + o] = ve;
    Ba[k * 256 + o] = va;
}

// ----------------- K5: small GEMM C[2048,256] = A[2048,656] @ B[656,256] (fp32)
__global__ void k_gemm_small(const float* __restrict__ A, const float* __restrict__ B,
                             float* __restrict__ C) {
    __shared__ float sA[16][64];
    __shared__ float sB[16][64];
    int bm = blockIdx.x, bn = blockIdx.y;
    int tid = threadIdx.x;
    int tx = tid & 15, ty = tid >> 4;
    float acc[4][4] = {};
    const float* Ab = A + bm * 64 * KDIM;
    const float* Bb = B + bn * 64;
    for (int kt = 0; kt < KDIM; kt += 16) {
        float4 av = *(const float4*)(Ab + (tid >> 2) * KDIM + kt + (tid & 3) * 4);
        int r = tid >> 2, k0 = (tid & 3) * 4;
        sA[k0 + 0][r] = av.x; sA[k0 + 1][r] = av.y; sA[k0 + 2][r] = av.z; sA[k0 + 3][r] = av.w;
        float4 bv = *(const float4*)(Bb + (kt + (tid >> 4)) * 256 + (tid & 15) * 4);
        *(float4*)&sB[tid >> 4][(tid & 15) * 4] = bv;
        __syncthreads();
#pragma unroll
        for (int kk = 0; kk < 16; ++kk) {
            float4 a4 = *(const float4*)&sA[kk][ty * 4];
            float4 b4 = *(const float4*)&sB[kk][tx * 4];
            float ar[4] = {a4.x, a4.y, a4.z, a4.w};
            float br[4] = {b4.x, b4.y, b4.z, b4.w};
#pragma unroll
            for (int ii = 0; ii < 4; ++ii)
#pragma unroll
                for (int jj = 0; jj < 4; ++jj) acc[ii][jj] = fmaf(ar[ii], br[jj], acc[ii][jj]);
        }
        __syncthreads();
    }
#pragma unroll
    for (int ii = 0; ii < 4; ++ii) {
        float4 v = {acc[ii][0], acc[ii][1], acc[ii][2], acc[ii][3]};
        *(float4*)(C + (bm * 64 + ty * 4 + ii) * 256 + bn * 64 + tx * 4) = v;
    }
}

// ----- K6: big GEMM over ally rows, A generated on-the-fly, passing-MLP epilogue
// Tile: 64 rows x 64 cols, blockIdx.y = head d (cols d*64..d*64+63).
// Epilogue: y = relu(E @ pass_w1 + pass_b1); p2[row, d, j] = y @ pass_w2 + pass_b2.
__global__ void k_gemm_ally(const float* __restrict__ ha1, const float* __restrict__ af,
                            const float* __restrict__ B,
                            const float* __restrict__ pw1, const float* __restrict__ pb1,
                            const float* __restrict__ pw2, const float* __restrict__ pb2,
                            float* __restrict__ p2) {
    __shared__ float s_h1[64][65];   // 4160
    __shared__ float s_af[64][10];   // 640
    __shared__ float sA[16][64];
    __shared__ float sB[16][64];
    __shared__ float s_pw1[64][64];  // 4096
    __shared__ float sE[64][68];     // E tile, then reused for y
    int bm = blockIdx.x, d = blockIdx.y;
    int tid = threadIdx.x;
    int tx = tid & 15, ty = tid >> 4;
    int row0 = bm * 64;

    for (int idx = tid; idx < 64 * 65; idx += 256) {
        int r = idx / 65, c = idx - r * 65;
        s_h1[r][c] = ha1[(row0 + r) * 65 + c];
    }
    for (int idx = tid; idx < 64 * 10; idx += 256) {
        int r = idx / 10, c = idx - r * 10;
        s_af[r][c] = af[(row0 + r) * ALD + c];
    }
    for (int idx = tid; idx < 64 * 64; idx += 256) s_pw1[idx >> 6][idx & 63] = pw1[idx];

    float acc[4][4] = {};
    for (int kt = 0; kt < KDIM; kt += 16) {
        __syncthreads();
        // generate A tile (U = outer(ha1_aug, af))
        int r = tid >> 2, k0 = (tid & 3) * 4;
#pragma unroll
        for (int j = 0; j < 4; ++j) {
            int k = kt + k0 + j;
            float v = 0.f;
            if (k < KTRUE) {
                int h = k / 10, i = k - h * 10;
                v = s_h1[r][h] * s_af[r][i];
            }
            sA[k0 + j][r] = v;
        }
        float4 bv = *(const float4*)(B + (kt + (tid >> 4)) * 256 + d * 64 + (tid & 15) * 4);
        *(float4*)&sB[tid >> 4][(tid & 15) * 4] = bv;
        __syncthreads();
#pragma unroll
        for (int kk = 0; kk < 16; ++kk) {
            float4 a4 = *(const float4*)&sA[kk][ty * 4];
            float4 b4 = *(const float4*)&sB[kk][tx * 4];
            float ar[4] = {a4.x, a4.y, a4.z, a4.w};
            float br[4] = {b4.x, b4.y, b4.z, b4.w};
#pragma unroll
            for (int ii = 0; ii < 4; ++ii)
#pragma unroll
                for (int jj = 0; jj < 4; ++jj) acc[ii][jj] = fmaf(ar[ii], br[jj], acc[ii][jj]);
        }
    }
    __syncthreads();
#pragma unroll
    for (int ii = 0; ii < 4; ++ii)
#pragma unroll
        for (int jj = 0; jj < 4; ++jj) sE[ty * 4 + ii][tx * 4 + jj] = acc[ii][jj];
    __syncthreads();
    // y = relu(E @ pw1 + pb1), thread (tx,ty) computes rows ty*4.., cols tx*4..
    float yv[4][4];
#pragma unroll
    for (int jj = 0; jj < 4; ++jj) {
        int hc = tx * 4 + jj;
        float b = pb1[hc];
#pragma unroll
        for (int ii = 0; ii < 4; ++ii) yv[ii][jj] = b;
    }
    for (int c = 0; c < 64; ++c) {
        float e0 = sE[ty * 4 + 0][c], e1 = sE[ty * 4 + 1][c], e2 = sE[ty * 4 + 2][c], e3 = sE[ty * 4 + 3][c];
#pragma unroll
        for (int jj = 0; jj < 4; ++jj) {
            float w = s_pw1[c][tx * 4 + jj];
            yv[0][jj] = fmaf(e0, w, yv[0][jj]);
            yv[1][jj] = fmaf(e1, w, yv[1][jj]);
            yv[2][jj] = fmaf(e2, w, yv[2][jj]);
            yv[3][jj] = fmaf(e3, w, yv[3][jj]);
        }
    }
    __syncthreads();
#pragma unroll
    for (int ii = 0; ii < 4; ++ii)
#pragma unroll
        for (int jj = 0; jj < 4; ++jj) sE[ty * 4 + ii][tx * 4 + jj] = fmaxf(yv[ii][jj], 0.f);
    __syncthreads();
    if (tid < 192) {
        int r = tid / 3, j = tid - r * 3;
        float s = pb2[j];
        for (int h = 0; h < 64; ++h) s = fmaf(sE[r][h], pw2[h * 3 + j], s);
        p2[(row0 + r) * 12 + d * 3 + j] = s;
    }
}

// ------------------- K7: per-agent merge + GRU + heads + output assembly
__global__ void k_final(const float* __restrict__ own, const float* __restrict__ hidden,
                        const float* __restrict__ fc1w, const float* __restrict__ fc1b,
                        const float* __restrict__ mergw,
                        const float* __restrict__ wih, const float* __restrict__ whh,
                        const float* __restrict__ bih, const float* __restrict__ bhh,
                        const float* __restrict__ f2w1, const float* __restrict__ f2b1,
                        const float* __restrict__ f2w2, const float* __restrict__ f2b2,
                        const float* __restrict__ emb_en, const float* __restrict__ emb_al,
                        const float* __restrict__ p2, float* __restrict__ out) {
    int ag = blockIdx.x, h = threadIdx.x;   // 64 threads
    __shared__ float sx[64], sh[64], sgi[192], sgh[192], shh[64], sq1[64];
    // own embedding
    float s = fc1b[h];
    const float* ow = own + ag * OWND;
#pragma unroll
    for (int c = 0; c < OWND; ++c) s = fmaf(ow[c], fc1w[c * H + h], s);
    // merger softmax over HD (per h)
    float m0 = mergw[h], m1 = mergw[64 + h], m2 = mergw[128 + h], m3 = mergw[192 + h];
    float mx = fmaxf(fmaxf(m0, m1), fmaxf(m2, m3));
    float e0 = __expf(m0 - mx), e1 = __expf(m1 - mx), e2 = __expf(m2 - mx), e3 = __expf(m3 - mx);
    float inv = 1.f / (e0 + e1 + e2 + e3);
    const float* een = emb_en + ag * 256;
    const float* eal = emb_al + ag * 256;
    float mg = (e0 * (een[h] + eal[h]) + e1 * (een[64 + h] + eal[64 + h]) +
                e2 * (een[128 + h] + eal[128 + h]) + e3 * (een[192 + h] + eal[192 + h])) * inv;
    float x = fmaxf(s + mg, 0.f);
    sx[h] = x;
    sh[h] = hidden[ag * 64 + h];
    __syncthreads();
    for (int g = h; g < 192; g += 64) {
        float a = bih[g], b = bhh[g];
        for (int c = 0; c < 64; ++c) {
            a = fmaf(sx[c], wih[g * 64 + c], a);
            b = fmaf(sh[c], whh[g * 64 + c], b);
        }
        sgi[g] = a; sgh[g] = b;
    }
    __syncthreads();
    float rg = 1.f / (1.f + __expf(-(sgi[h] + sgh[h])));
    float zg = 1.f / (1.f + __expf(-(sgi[64 + h] + sgh[64 + h])));
    float ng = tanhf(sgi[128 + h] + rg * sgh[128 + h]);
    float hv = (1.f - zg) * ng + zg * sh[h];
    shh[h] = hv;
    __syncthreads();
    float q1 = f2b1[h];
    for (int c = 0; c < 64; ++c) q1 = fmaf(shh[c], f2w1[c * 64 + h], q1);
    sq1[h] = fmaxf(q1, 0.f);
    __syncthreads();
    float* qout = out + ag * 22;
    if (h < 19) {
        float s2 = f2b2[h];
        for (int c = 0; c < 64; ++c) s2 = fmaf(sq1[c], f2w2[c * 19 + h], s2);
        qout[(h < 9) ? h : h + 3] = s2;
    }
    if (h >= 32 && h < 35) {
        int j = h - 32;
        float best = -1e30f;
        const float* pp = p2 + ag * NALY * 12;
        for (int l = 0; l < NALY; ++l) {
            float mean = 0.25f * (pp[l * 12 + j] + pp[l * 12 + 3 + j] + pp[l * 12 + 6 + j] + pp[l * 12 + 9 + j]);
            best = fmaxf(best, mean);
        }
        qout[9 + j] = best;
    }
    out[QOFF + ag * 64 + h] = hv;
}

extern "C" void kernel_launch(void* const* d_in, const int* in_sizes, int n_in,
                              void* d_out, int out_size, void* d_ws, size_t ws_size,
                              hipStream_t stream) {
    const float* own    = (const float*)d_in[1];
    const float* allyf  = (const float*)d_in[2];
    const float* enemyf = (const float*)d_in[3];
    const float* hidden = (const float*)d_in[4];
    const float* fc1w   = (const float*)d_in[5];
    const float* fc1b   = (const float*)d_in[6];
    const float* hew1   = (const float*)d_in[7];
    const float* heb1   = (const float*)d_in[8];
    const float* hew2   = (const float*)d_in[9];
    const float* heb2   = (const float*)d_in[10];
    const float* haw1   = (const float*)d_in[11];
    const float* hab1   = (const float*)d_in[12];
    const float* haw2   = (const float*)d_in[13];
    const float* hab2   = (const float*)d_in[14];
    const float* mergw  = (const float*)d_in[15];
    const float* wih    = (const float*)d_in[16];
    const float* whh    = (const float*)d_in[17];
    const float* bih    = (const float*)d_in[18];
    const float* bhh    = (const float*)d_in[19];
    const float* f2w1   = (const float*)d_in[20];
    const float* f2b1   = (const float*)d_in[21];
    const float* f2w2   = (const float*)d_in[22];
    const float* f2b2   = (const float*)d_in[23];
    const float* pw1    = (const float*)d_in[24];
    const float* pb1    = (const float*)d_in[25];
    const float* pw2    = (const float*)d_in[26];
    const float* pb2    = (const float*)d_in[27];
    float* out = (float*)d_out;

    // workspace layout (floats); total ~25.7 MB
    float* W      = (float*)d_ws;
    float* ha1    = W;                      // 30720*65
    float* usum_e = ha1 + 30720 * 65;       // 2048*656
    float* usum_a = usum_e + RAG * KDIM;    // 2048*656
    float* Be     = usum_a + RAG * KDIM;    // 656*256
    float* Ba     = Be + KDIM * 256;        // 656*256
    float* emb_en = Ba + KDIM * 256;        // 2048*256
    float* emb_al = emb_en + RAG * 256;     // 2048*256
    float* p2     = emb_al + RAG * 256;     // 30720*12

    k_reorder_B<<<KDIM, 256, 0, stream>>>(hew2, heb2, haw2, hab2, Be, Ba);
    k_prep_ally<<<(AROWS * 64) / 256, 256, 0, stream>>>(allyf, haw1, hab1, ha1);
    k_enemy_usum<<<RAG, 256, 0, stream>>>(enemyf, hew1, heb1, usum_e);
    k_ally_usum<<<RAG, 256, 0, stream>>>(allyf, ha1, usum_a);
    k_gemm_small<<<dim3(RAG / 64, 4), 256, 0, stream>>>(usum_e, Be, emb_en);
    k_gemm_small<<<dim3(RAG / 64, 4), 256, 0, stream>>>(usum_a, Ba, emb_al);
    k_gemm_ally<<<dim3(AROWS / 64, 4), 256, 0, stream>>>(ha1, allyf, Ba, pw1, pb1, pw2, pb2, p2);
    k_final<<<RAG, 64, 0, stream>>>(own, hidden, fc1w, fc1b, mergw, wih, whh, bih, bhh,
                                    f2w1, f2b1, f2w2, f2b2, emb_en, emb_al, p2, out);
}

// Round 3
// 194.841 us; speedup vs baseline: 2.3008x; 2.3008x over previous
//
#include <hip/hip_runtime.h>
#include <hip/hip_bf16.h>

#define RAG   2048          // BS*NA
#define AROWS 30720         // RAG*15 ally rows
#define KP    672           // padded K (real 650): k' = i*64+h for k'<640, aug 640..649
#define QOFF  45056         // 128*16*22

typedef __attribute__((ext_vector_type(8))) short short8;
typedef __attribute__((ext_vector_type(4))) float f32x4;

__device__ inline unsigned short f2bf(float f){
    unsigned u = __float_as_uint(f);
    u += 0x7fffu + ((u >> 16) & 1u);            // RNE
    return (unsigned short)(u >> 16);
}
__device__ inline float bf2f(unsigned short s){ return __uint_as_float(((unsigned)s) << 16); }
__device__ inline unsigned pack2(float a, float b){
    return (unsigned)f2bf(a) | ((unsigned)f2bf(b) << 16);
}

// ---------------- K1: reorder hypernet W2/b2 into Bt[n][k'] bf16 + ally h1 (bf16) ----------------
__global__ void __launch_bounds__(256) k_prep(
    const float* __restrict__ hew2, const float* __restrict__ heb2,
    const float* __restrict__ haw2, const float* __restrict__ hab2,
    const float* __restrict__ allyf, const float* __restrict__ haw1, const float* __restrict__ hab1,
    unsigned short* __restrict__ Bte, unsigned short* __restrict__ Bta,
    unsigned short* __restrict__ ha1)
{
    int bb = blockIdx.x, tid = threadIdx.x;
    if (bb < 256){
        int n = bb;
        for (int k = tid; k < KP; k += 256){
            unsigned short ve = 0, va = 0;
            if (k < 640){
                int h = k & 63, i = k >> 6;
                ve = f2bf(hew2[h*2820 + i*256 + n]);
                va = f2bf(haw2[h*2560 + i*256 + n]);
            } else if (k < 650){
                int i = k - 640;
                ve = f2bf(heb2[i*256 + n]);
                va = f2bf(hab2[i*256 + n]);
            }
            Bte[n*KP + k] = ve;
            Bta[n*KP + k] = va;
        }
    } else {
        int r = (bb - 256)*4 + (tid >> 6), h = tid & 63;
        const float* a = allyf + r*10;
        float s = hab1[h];
#pragma unroll
        for (int i = 0; i < 10; ++i) s = fmaf(a[i], haw1[i*64 + h], s);
        ha1[r*64 + h] = f2bf(fmaxf(s, 0.f));
    }
}

// ---------------- K2: per-agent Usum rows (enemy + ally), bf16 [4096][672] ----------------
__global__ void __launch_bounds__(256) k_usum(
    const float* __restrict__ ef, const float* __restrict__ hew1, const float* __restrict__ heb1,
    const float* __restrict__ af, const unsigned short* __restrict__ ha1,
    unsigned short* __restrict__ usum)
{
    __shared__ float s_ef[16][10], s_af[15][10];
    __shared__ float s_he[16][64], s_ha[15][64];
    int ag = blockIdx.x, tid = threadIdx.x;
    if (tid < 160) s_ef[tid/10][tid%10] = ef[ag*160 + tid];
    if (tid < 150) s_af[tid/10][tid%10] = af[ag*150 + tid];
    __syncthreads();
    for (int idx = tid; idx < 16*64; idx += 256){
        int en = idx >> 6, h = idx & 63;
        float s = heb1[h];
#pragma unroll
        for (int i = 0; i < 10; ++i) s = fmaf(s_ef[en][i], hew1[i*64 + h], s);
        s_he[en][h] = fmaxf(s, 0.f);
    }
    for (int idx = tid; idx < 15*64; idx += 256){
        int l = idx >> 6, h = idx & 63;
        s_ha[l][h] = bf2f(ha1[(ag*15 + l)*64 + h]);
    }
    __syncthreads();
    for (int k = tid; k < KP; k += 256){
        float ue = 0.f, ua = 0.f;
        if (k < 640){
            int i = k >> 6, h = k & 63;
#pragma unroll
            for (int en = 0; en < 16; ++en) ue = fmaf(s_he[en][h], s_ef[en][i], ue);
#pragma unroll
            for (int l = 0; l < 15; ++l) ua = fmaf(s_ha[l][h], s_af[l][i], ua);
        } else if (k < 650){
            int i = k - 640;
#pragma unroll
            for (int en = 0; en < 16; ++en) ue += s_ef[en][i];
#pragma unroll
            for (int l = 0; l < 15; ++l) ua += s_af[l][i];
        }
        usum[ag*KP + k]         = f2bf(ue);
        usum[(RAG + ag)*KP + k] = f2bf(ua);
    }
}

// ---------------- K3: MFMA GEMMs. blocks 0..479: ally rows (A generated on-the-fly,
// passing-MLP epilogue). blocks 480..543: stacked usum rows -> emb. ----------------
__global__ void __launch_bounds__(256, 2) k_gemm(
    const unsigned short* __restrict__ Bte, const unsigned short* __restrict__ Bta,
    const unsigned short* __restrict__ ha1, const float* __restrict__ af,
    const unsigned short* __restrict__ usum,
    const float* __restrict__ pw1, const float* __restrict__ pb1,
    const float* __restrict__ pw2, const float* __restrict__ pb2,
    float* __restrict__ emb, float* __restrict__ p2)
{
    __shared__ __align__(16) char smem[46080];
    unsigned short* sB  = (unsigned short*)smem;            // [256][40] bf16
    unsigned short* sA  = (unsigned short*)(smem + 20480);  // [64][40]
    unsigned short* sH  = (unsigned short*)(smem + 25600);  // [64][72]
    unsigned short* sW1 = (unsigned short*)(smem + 36864);  // [64][72] pw1^T

    int tid = threadIdx.x;
    int w = tid >> 6;
    int lane = tid & 63;
    int l15 = lane & 15, quad = lane >> 4;
    int bb = blockIdx.x;

    f32x4 acc[4][4];
#pragma unroll
    for (int a = 0; a < 4; ++a)
#pragma unroll
    for (int b = 0; b < 4; ++b) acc[a][b] = (f32x4){0.f, 0.f, 0.f, 0.f};

    if (bb < 480){
        int row0 = bb * 64;
        int r = tid >> 2, c = tid & 3;
#pragma unroll
        for (int p = 0; p < 2; ++p){
            int ch = tid + p*256;
            int rr = ch >> 3, cc = ch & 7;
            *(uint4*)&sH[rr*72 + cc*8] = *(const uint4*)&ha1[(row0 + rr)*64 + cc*8];
        }
#pragma unroll
        for (int p = 0; p < 16; ++p){
            int idx = tid + p*256;
            sW1[(idx & 63)*72 + (idx >> 6)] = f2bf(pw1[idx]);
        }
        float af_reg[10];
        {
            const float* ap = af + (row0 + r)*10;
#pragma unroll
            for (int i = 0; i < 10; ++i) af_reg[i] = ap[i];
        }
        __syncthreads();
        float h1f[16];
        {
            uint4 ra = *(const uint4*)&sH[r*72 + c*8];
            uint4 rb = *(const uint4*)&sH[r*72 + 32 + c*8];
            unsigned va[4] = {ra.x, ra.y, ra.z, ra.w};
            unsigned vb[4] = {rb.x, rb.y, rb.z, rb.w};
#pragma unroll
            for (int q = 0; q < 4; ++q){
                h1f[q*2+0]   = __uint_as_float(va[q] << 16);
                h1f[q*2+1]   = __uint_as_float(va[q] & 0xffff0000u);
                h1f[8+q*2+0] = __uint_as_float(vb[q] << 16);
                h1f[8+q*2+1] = __uint_as_float(vb[q] & 0xffff0000u);
            }
        }
        const unsigned short* Btb = Bta + tid*KP;
#pragma unroll
        for (int i = 0; i < 10; ++i){
#pragma unroll
            for (int hb = 0; hb < 2; ++hb){
                int kt = i*64 + hb*32;
                __syncthreads();
                uint4 bq0 = *(const uint4*)&Btb[kt + 0];
                uint4 bq1 = *(const uint4*)&Btb[kt + 8];
                uint4 bq2 = *(const uint4*)&Btb[kt + 16];
                uint4 bq3 = *(const uint4*)&Btb[kt + 24];
                float avf = af_reg[i];
                uint4 pk;
                pk.x = pack2(h1f[hb*8+0]*avf, h1f[hb*8+1]*avf);
                pk.y = pack2(h1f[hb*8+2]*avf, h1f[hb*8+3]*avf);
                pk.z = pack2(h1f[hb*8+4]*avf, h1f[hb*8+5]*avf);
                pk.w = pack2(h1f[hb*8+6]*avf, h1f[hb*8+7]*avf);
                *(uint4*)&sA[r*40 + c*8] = pk;
                *(uint4*)&sB[tid*40 + 0]  = bq0;
                *(uint4*)&sB[tid*40 + 8]  = bq1;
                *(uint4*)&sB[tid*40 + 16] = bq2;
                *(uint4*)&sB[tid*40 + 24] = bq3;
                __syncthreads();
                short8 a_[4], b_[4];
#pragma unroll
                for (int mt = 0; mt < 4; ++mt) a_[mt] = *(const short8*)&sA[(mt*16 + l15)*40 + quad*8];
#pragma unroll
                for (int nt = 0; nt < 4; ++nt) b_[nt] = *(const short8*)&sB[(w*64 + nt*16 + l15)*40 + quad*8];
#pragma unroll
                for (int mt = 0; mt < 4; ++mt)
#pragma unroll
                for (int nt = 0; nt < 4; ++nt)
                    acc[mt][nt] = __builtin_amdgcn_mfma_f32_16x16x32_bf16(a_[mt], b_[nt], acc[mt][nt], 0, 0, 0);
            }
        }
        {   // tail kstep: aug rows 640..649 (A = af[i]), 650..671 zero
            int kt = 640;
            __syncthreads();
            uint4 bq0 = *(const uint4*)&Btb[kt + 0];
            uint4 bq1 = *(const uint4*)&Btb[kt + 8];
            uint4 bq2 = *(const uint4*)&Btb[kt + 16];
            uint4 bq3 = *(const uint4*)&Btb[kt + 24];
            float v0=0.f,v1=0.f,v2=0.f,v3=0.f,v4=0.f,v5=0.f,v6=0.f,v7=0.f;
            if (c == 0){ v0=af_reg[0]; v1=af_reg[1]; v2=af_reg[2]; v3=af_reg[3];
                         v4=af_reg[4]; v5=af_reg[5]; v6=af_reg[6]; v7=af_reg[7]; }
            else if (c == 1){ v0 = af_reg[8]; v1 = af_reg[9]; }
            uint4 pk;
            pk.x = pack2(v0, v1); pk.y = pack2(v2, v3);
            pk.z = pack2(v4, v5); pk.w = pack2(v6, v7);
            *(uint4*)&sA[r*40 + c*8] = pk;
            *(uint4*)&sB[tid*40 + 0]  = bq0;
            *(uint4*)&sB[tid*40 + 8]  = bq1;
            *(uint4*)&sB[tid*40 + 16] = bq2;
            *(uint4*)&sB[tid*40 + 24] = bq3;
            __syncthreads();
            short8 a_[4], b_[4];
#pragma unroll
            for (int mt = 0; mt < 4; ++mt) a_[mt] = *(const short8*)&sA[(mt*16 + l15)*40 + quad*8];
#pragma unroll
            for (int nt = 0; nt < 4; ++nt) b_[nt] = *(const short8*)&sB[(w*64 + nt*16 + l15)*40 + quad*8];
#pragma unroll
            for (int mt = 0; mt < 4; ++mt)
#pragma unroll
            for (int nt = 0; nt < 4; ++nt)
                acc[mt][nt] = __builtin_amdgcn_mfma_f32_16x16x32_bf16(a_[mt], b_[nt], acc[mt][nt], 0, 0, 0);
        }
        // ---- fused passing-MLP epilogue: wave w == head d ----
        __syncthreads();   // all K-loop LDS reads done; reuse region for sE
        unsigned short* sE = (unsigned short*)(smem + w*9216); // [64][72] bf16, E tile of head w
#pragma unroll
        for (int mt = 0; mt < 4; ++mt)
#pragma unroll
        for (int nt = 0; nt < 4; ++nt)
#pragma unroll
        for (int rg = 0; rg < 4; ++rg)
            sE[(mt*16 + quad*4 + rg)*72 + nt*16 + l15] = f2bf(acc[mt][nt][rg]);
        __syncthreads();
        f32x4 yacc[4][4];
#pragma unroll
        for (int a = 0; a < 4; ++a)
#pragma unroll
        for (int b = 0; b < 4; ++b) yacc[a][b] = (f32x4){0.f, 0.f, 0.f, 0.f};
#pragma unroll
        for (int kb = 0; kb < 2; ++kb){
            short8 ea[4], wb[4];
#pragma unroll
            for (int mt = 0; mt < 4; ++mt) ea[mt] = *(const short8*)&sE[(mt*16 + l15)*72 + kb*32 + quad*8];
#pragma unroll
            for (int ot = 0; ot < 4; ++ot) wb[ot] = *(const short8*)&sW1[(ot*16 + l15)*72 + kb*32 + quad*8];
#pragma unroll
            for (int mt = 0; mt < 4; ++mt)
#pragma unroll
            for (int ot = 0; ot < 4; ++ot)
                yacc[mt][ot] = __builtin_amdgcn_mfma_f32_16x16x32_bf16(ea[mt], wb[ot], yacc[mt][ot], 0, 0, 0);
        }
        float pb1v[4], w2r[4][3];
#pragma unroll
        for (int ot = 0; ot < 4; ++ot){
            pb1v[ot] = pb1[ot*16 + l15];
#pragma unroll
            for (int j = 0; j < 3; ++j) w2r[ot][j] = pw2[(ot*16 + l15)*3 + j];
        }
#pragma unroll
        for (int mt = 0; mt < 4; ++mt){
            float part[4][3];
#pragma unroll
            for (int rg = 0; rg < 4; ++rg)
#pragma unroll
            for (int j = 0; j < 3; ++j) part[rg][j] = 0.f;
#pragma unroll
            for (int ot = 0; ot < 4; ++ot)
#pragma unroll
            for (int rg = 0; rg < 4; ++rg){
                float yv = fmaxf(yacc[mt][ot][rg] + pb1v[ot], 0.f);
#pragma unroll
                for (int j = 0; j < 3; ++j) part[rg][j] = fmaf(yv, w2r[ot][j], part[rg][j]);
            }
#pragma unroll
            for (int off = 1; off < 16; off <<= 1)
#pragma unroll
            for (int rg = 0; rg < 4; ++rg)
#pragma unroll
            for (int j = 0; j < 3; ++j) part[rg][j] += __shfl_xor(part[rg][j], off, 64);
            if (l15 == 0){
#pragma unroll
                for (int rg = 0; rg < 4; ++rg)
#pragma unroll
                for (int j = 0; j < 3; ++j)
                    p2[(row0 + mt*16 + quad*4 + rg)*12 + w*3 + j] = part[rg][j] + pb2[j];
            }
        }
    } else {
        // ---- small GEMM: stacked usum [4096][672] @ Bt -> emb [4096][256] fp32 ----
        int row0 = (bb - 480) * 64;
        const unsigned short* Btb = ((row0 < RAG) ? Bte : Bta) + tid*KP;
        const unsigned short* Ab  = usum + (row0 + (tid >> 2))*KP + (tid & 3)*8;
        int r = tid >> 2, c = tid & 3;
        for (int kt = 0; kt < KP; kt += 32){
            __syncthreads();
            uint4 aq  = *(const uint4*)&Ab[kt];
            uint4 bq0 = *(const uint4*)&Btb[kt + 0];
            uint4 bq1 = *(const uint4*)&Btb[kt + 8];
            uint4 bq2 = *(const uint4*)&Btb[kt + 16];
            uint4 bq3 = *(const uint4*)&Btb[kt + 24];
            *(uint4*)&sA[r*40 + c*8] = aq;
            *(uint4*)&sB[tid*40 + 0]  = bq0;
            *(uint4*)&sB[tid*40 + 8]  = bq1;
            *(uint4*)&sB[tid*40 + 16] = bq2;
            *(uint4*)&sB[tid*40 + 24] = bq3;
            __syncthreads();
            short8 a_[4], b_[4];
#pragma unroll
            for (int mt = 0; mt < 4; ++mt) a_[mt] = *(const short8*)&sA[(mt*16 + l15)*40 + quad*8];
#pragma unroll
            for (int nt = 0; nt < 4; ++nt) b_[nt] = *(const short8*)&sB[(w*64 + nt*16 + l15)*40 + quad*8];
#pragma unroll
            for (int mt = 0; mt < 4; ++mt)
#pragma unroll
            for (int nt = 0; nt < 4; ++nt)
                acc[mt][nt] = __builtin_amdgcn_mfma_f32_16x16x32_bf16(a_[mt], b_[nt], acc[mt][nt], 0, 0, 0);
        }
#pragma unroll
        for (int mt = 0; mt < 4; ++mt)
#pragma unroll
        for (int nt = 0; nt < 4; ++nt)
#pragma unroll
        for (int rg = 0; rg < 4; ++rg)
            emb[(row0 + mt*16 + quad*4 + rg)*256 + w*64 + nt*16 + l15] = acc[mt][nt][rg];
    }
}

// ---------------- K4: merge + GRU + heads, 8 agents per block ----------------
__global__ void __launch_bounds__(512) k_final(
    const float* __restrict__ own, const float* __restrict__ hidden,
    const float* __restrict__ fc1w, const float* __restrict__ fc1b,
    const float* __restrict__ mergw,
    const float* __restrict__ wih, const float* __restrict__ whh,
    const float* __restrict__ bih, const float* __restrict__ bhh,
    const float* __restrict__ f2w1, const float* __restrict__ f2b1,
    const float* __restrict__ f2w2, const float* __restrict__ f2b2,
    const float* __restrict__ emb, const float* __restrict__ p2,
    float* __restrict__ out)
{
    int tid = threadIdx.x;
    int al = tid >> 6, h = tid & 63;
    int ag = blockIdx.x * 8 + al;
    __shared__ float sx[8][64], sh[8][64], sgi[8][192], sgh[8][192], shh[8][64], sq1[8][64];

    float s = fc1b[h];
    const float* ow = own + ag*30;
#pragma unroll
    for (int c = 0; c < 30; ++c) s = fmaf(ow[c], fc1w[c*64 + h], s);
    float m0 = mergw[h], m1 = mergw[64+h], m2 = mergw[128+h], m3 = mergw[192+h];
    float mx = fmaxf(fmaxf(m0, m1), fmaxf(m2, m3));
    float e0 = __expf(m0-mx), e1 = __expf(m1-mx), e2 = __expf(m2-mx), e3 = __expf(m3-mx);
    float inv = 1.f / (e0+e1+e2+e3);
    const float* een = emb + ag*256;
    const float* eal = emb + (RAG + ag)*256;
    float mg = (e0*(een[h]+eal[h]) + e1*(een[64+h]+eal[64+h]) +
                e2*(een[128+h]+eal[128+h]) + e3*(een[192+h]+eal[192+h])) * inv;
    sx[al][h] = fmaxf(s + mg, 0.f);
    sh[al][h] = hidden[ag*64 + h];
    __syncthreads();
    for (int g = h; g < 192; g += 64){
        float a = bih[g], b = bhh[g];
        for (int c0 = 0; c0 < 64; ++c0){
            a = fmaf(sx[al][c0], wih[g*64 + c0], a);
            b = fmaf(sh[al][c0], whh[g*64 + c0], b);
        }
        sgi[al][g] = a; sgh[al][g] = b;
    }
    __syncthreads();
    float rg = 1.f / (1.f + __expf(-(sgi[al][h] + sgh[al][h])));
    float zg = 1.f / (1.f + __expf(-(sgi[al][64+h] + sgh[al][64+h])));
    float ng = tanhf(sgi[al][128+h] + rg * sgh[al][128+h]);
    float hv = (1.f - zg)*ng + zg*sh[al][h];
    shh[al][h] = hv;
    __syncthreads();
    float q1 = f2b1[h];
    for (int c0 = 0; c0 < 64; ++c0) q1 = fmaf(shh[al][c0], f2w1[c0*64 + h], q1);
    sq1[al][h] = fmaxf(q1, 0.f);
    __syncthreads();
    float* qout = out + ag*22;
    if (h < 19){
        float s2 = f2b2[h];
        for (int c0 = 0; c0 < 64; ++c0) s2 = fmaf(sq1[al][c0], f2w2[c0*19 + h], s2);
        qout[(h < 9) ? h : h + 3] = s2;
    }
    if (h >= 32 && h < 35){
        int j = h - 32;
        float best = -1e30f;
        const float* pp = p2 + ag*15*12;
        for (int l = 0; l < 15; ++l){
            float mean = 0.25f*(pp[l*12+j] + pp[l*12+3+j] + pp[l*12+6+j] + pp[l*12+9+j]);
            best = fmaxf(best, mean);
        }
        qout[9 + j] = best;
    }
    out[QOFF + ag*64 + h] = hv;
}

extern "C" void kernel_launch(void* const* d_in, const int* in_sizes, int n_in,
                              void* d_out, int out_size, void* d_ws, size_t ws_size,
                              hipStream_t stream) {
    const float* own    = (const float*)d_in[1];
    const float* allyf  = (const float*)d_in[2];
    const float* enemyf = (const float*)d_in[3];
    const float* hidden = (const float*)d_in[4];
    const float* fc1w   = (const float*)d_in[5];
    const float* fc1b   = (const float*)d_in[6];
    const float* hew1   = (const float*)d_in[7];
    const float* heb1   = (const float*)d_in[8];
    const float* hew2   = (const float*)d_in[9];
    const float* heb2   = (const float*)d_in[10];
    const float* haw1   = (const float*)d_in[11];
    const float* hab1   = (const float*)d_in[12];
    const float* haw2   = (const float*)d_in[13];
    const float* hab2   = (const float*)d_in[14];
    const float* mergw  = (const float*)d_in[15];
    const float* wih    = (const float*)d_in[16];
    const float* whh    = (const float*)d_in[17];
    const float* bih    = (const float*)d_in[18];
    const float* bhh    = (const float*)d_in[19];
    const float* f2w1   = (const float*)d_in[20];
    const float* f2b1   = (const float*)d_in[21];
    const float* f2w2   = (const float*)d_in[22];
    const float* f2b2   = (const float*)d_in[23];
    const float* pw1    = (const float*)d_in[24];
    const float* pb1    = (const float*)d_in[25];
    const float* pw2    = (const float*)d_in[26];
    const float* pb2    = (const float*)d_in[27];
    float* out = (float*)d_out;

    char* W = (char*)d_ws;
    unsigned short* Bte  = (unsigned short*)(W + 0);         // 256*672*2   = 344064
    unsigned short* Bta  = (unsigned short*)(W + 344064);    // 344064
    unsigned short* ha1  = (unsigned short*)(W + 688128);    // 30720*64*2  = 3932160
    unsigned short* usum = (unsigned short*)(W + 4620288);   // 4096*672*2  = 5505024
    float*          emb  = (float*)(W + 10125312);           // 4096*256*4  = 4194304
    float*          p2   = (float*)(W + 14319616);           // 30720*12*4  = 1474560

    k_prep<<<256 + 7680, 256, 0, stream>>>(hew2, heb2, haw2, hab2, allyf, haw1, hab1, Bte, Bta, ha1);
    k_usum<<<RAG, 256, 0, stream>>>(enemyf, hew1, heb1, allyf, ha1, usum);
    k_gemm<<<480 + 64, 256, 0, stream>>>(Bte, Bta, ha1, allyf, usum, pw1, pb1, pw2, pb2, emb, p2);
    k_final<<<RAG/8, 512, 0, stream>>>(own, hidden, fc1w, fc1b, mergw, wih, whh, bih, bhh,
                                       f2w1, f2b1, f2w2, f2b2, emb, p2, out);
}